// Round 17
// baseline (130.785 us; speedup 1.0000x reference)
//
#include <hip/hip_runtime.h>
#include <hip/hip_bf16.h>

#define B_    2
#define S_    2048
#define DIN   1024
#define EMB   1024
#define NH    16
#define HD    64
#define N3    3072
#define MROWS 4096   // B_*S_
#define KVB   64
#define QBLK  128
#define NT    (S_ / KVB)   // 32 kv tiles
#define NTS   16           // tiles per half-wave

typedef short bf16x8 __attribute__((ext_vector_type(8)));
typedef float f32x4  __attribute__((ext_vector_type(4)));
typedef float f32x16 __attribute__((ext_vector_type(16)));
typedef unsigned short u16;
typedef u16 u16x8 __attribute__((ext_vector_type(8)));
typedef u16 u16x4 __attribute__((ext_vector_type(4)));
typedef unsigned int u32;

__device__ __forceinline__ u16 f2bf(float f) {
  union { float f; unsigned u; } x; x.f = f;
  unsigned r = x.u + 0x7fffu + ((x.u >> 16) & 1u);
  return (u16)(r >> 16);
}

__device__ __forceinline__ u32 cvtpk(float lo, float hi) {
  u32 r;
  asm("v_cvt_pk_bf16_f32 %0, %1, %2" : "=v"(r) : "v"(lo), "v"(hi));
  return r;
}

__device__ __forceinline__ void gload16(const void* g, void* l) {
  __builtin_amdgcn_global_load_lds(
      (const __attribute__((address_space(1))) unsigned int*)g,
      (__attribute__((address_space(3))) unsigned int*)l, 16, 0, 0);
}

#define BARRIER() do { asm volatile("" ::: "memory"); \
                       __builtin_amdgcn_s_barrier();  \
                       asm volatile("" ::: "memory"); } while (0)

// one fused cast: x (1048576 float4) + qkv_w (786432) + o_w (262144)
__global__ __launch_bounds__(256)
void cast_all(const float* __restrict__ x, const float* __restrict__ w1,
              const float* __restrict__ w2, u16* __restrict__ ox,
              u16* __restrict__ ow1, u16* __restrict__ ow2) {
  const int i = blockIdx.x * 256 + threadIdx.x;   // 0..2097151
  const float* src; u16* dst; int off;
  if (i < 1048576)              { src = x;  dst = ox;  off = i; }
  else if (i < 1048576 + 786432){ src = w1; dst = ow1; off = i - 1048576; }
  else                          { src = w2; dst = ow2; off = i - 1835008; }
  const float4 v = ((const float4*)src)[off];
  u16x4 o;
  o[0] = f2bf(v.x); o[1] = f2bf(v.y); o[2] = f2bf(v.z); o[3] = f2bf(v.w);
  ((u16x4*)dst)[off] = o;
}

// QKV projection GEMM (round-16 verified): 128x128, BK=32, dbuf LDS, depth-1
// counted-vmcnt prefetch, XCD-grouped n-outer block decode.
__global__ __launch_bounds__(256)
void gemm_qkv(const u16* __restrict__ A, const u16* __restrict__ W,
              const float* __restrict__ bias,
              u16* __restrict__ Qb, u16* __restrict__ Kb, u16* __restrict__ VbT) {
  __shared__ u16 Als[2][128 * 32];
  __shared__ u16 Bls[2][128 * 32];
  const int K = DIN;
  const int tid  = threadIdx.x;
  const int wave = tid >> 6, lane = tid & 63;
  const int lhi  = lane >> 4, llo = lane & 15;
  const int wr   = wave >> 1, wc = wave & 1;
  const int bid  = blockIdx.x;               // 0..767
  const int xcd  = bid & 7, i = bid >> 3;    // i: 0..95
  const int m0   = (xcd * 4 + (i & 3)) * 128;
  const int n0   = (i >> 2) * 128;
  const int KT   = K >> 5;

  f32x4 acc[4][4];
#pragma unroll
  for (int m = 0; m < 4; ++m)
#pragma unroll
    for (int n = 0; n < 4; ++n) acc[m][n] = f32x4{0.f, 0.f, 0.f, 0.f};

  auto issue = [&](int t) {
#pragma unroll
    for (int j = 0; j < 2; ++j) {
      const int e   = (tid + j * 256) * 8;   // element index in [128][32] tile
      const int row = e >> 5, col = e & 31;
      gload16(A + (size_t)(m0 + row) * K + t * 32 + col,
              (char*)Als[t & 1] + wave * 1024 + j * 4096);
      gload16(W + (size_t)(n0 + row) * K + t * 32 + col,
              (char*)Bls[t & 1] + wave * 1024 + j * 4096);
    }
  };

  issue(0);                                        // 4 outstanding
  for (int t = 0; t < KT; ++t) {
    if (t + 1 < KT) {
      issue(t + 1);                                // 8 outstanding
      asm volatile("s_waitcnt vmcnt(4)" ::: "memory");  // tile t landed
    } else {
      asm volatile("s_waitcnt vmcnt(0)" ::: "memory");
    }
    BARRIER();
    const u16* Ab = Als[t & 1];
    const u16* Bb = Bls[t & 1];
    bf16x8 af[4], bfr[4];
#pragma unroll
    for (int m = 0; m < 4; ++m) af[m]  = *(const bf16x8*)&Ab[(wr * 64 + m * 16 + llo) * 32 + lhi * 8];
#pragma unroll
    for (int n = 0; n < 4; ++n) bfr[n] = *(const bf16x8*)&Bb[(wc * 64 + n * 16 + llo) * 32 + lhi * 8];
#pragma unroll
    for (int m = 0; m < 4; ++m)
#pragma unroll
      for (int n = 0; n < 4; ++n)
        acc[m][n] = __builtin_amdgcn_mfma_f32_16x16x32_bf16(af[m], bfr[n], acc[m][n], 0, 0, 0);
    BARRIER();
  }

#pragma unroll
  for (int n = 0; n < 4; ++n) {
    const int colb = n0 + wc * 64 + n * 16;  // 16-aligned; within one 64-col section
    const int gcol = colb + llo;
    const float bv = bias[gcol];
    const int h   = colb / 192;
    const int rr  = colb - h * 192;
    const int sec = rr >> 6;                 // 0:Q 1:K 2:V
    const int d   = (rr & 63) + llo;
#pragma unroll
    for (int m = 0; m < 4; ++m) {
      const int rowb = m0 + wr * 64 + m * 16 + lhi * 4;
      const int b = rowb >> 11, s0 = rowb & 2047;
      if (sec == 2) {
        u16x4 vv;
#pragma unroll
        for (int r = 0; r < 4; ++r) vv[r] = f2bf(acc[m][n][r] + bv);
        *(u16x4*)&VbT[((size_t)(b * NH + h) * HD + d) * S_ + s0] = vv;
      } else {
        u16* dst = (sec == 0) ? Qb : Kb;
        const float scl = (sec == 0) ? 0.18033688f : 1.0f;  // 0.125*log2(e)
#pragma unroll
        for (int r = 0; r < 4; ++r)
          dst[(((size_t)(b * NH + h) * S_ + s0 + r) << 6) + d] = f2bf((acc[m][n][r] + bv) * scl);
      }
    }
  }
}

// Out-projection GEMM (round-16 verified): M-split 64x128, XCD-grouped decode.
__global__ __launch_bounds__(256)
void gemm_out_m64(const u16* __restrict__ A, const u16* __restrict__ W,
                  const float* __restrict__ bias, float* __restrict__ Cf,
                  int M, int N, int K) {
  __shared__ u16 Als[2][64 * 32];
  __shared__ u16 Bls[2][128 * 32];
  const int tid  = threadIdx.x;
  const int wave = tid >> 6, lane = tid & 63;
  const int lhi  = lane >> 4, llo = lane & 15;
  const int wr   = wave >> 1, wc = wave & 1;
  const int bid  = blockIdx.x;               // 0..511
  const int xcd  = bid & 7, i = bid >> 3;    // i: 0..63
  const int m0   = (xcd * 8 + (i & 7)) * 64;
  const int n0   = (i >> 3) * 128;
  const int KT   = K >> 5;

  f32x4 acc[2][4];
#pragma unroll
  for (int m = 0; m < 2; ++m)
#pragma unroll
    for (int n = 0; n < 4; ++n) acc[m][n] = f32x4{0.f, 0.f, 0.f, 0.f};

  auto issue = [&](int t) {
    {
      const int row = tid >> 2, col = (tid & 3) * 8;
      gload16(A + (size_t)(m0 + row) * K + t * 32 + col,
              (char*)Als[t & 1] + wave * 1024);
    }
#pragma unroll
    for (int j = 0; j < 2; ++j) {
      const int e   = (tid + j * 256) * 8;
      const int row = e >> 5, col = e & 31;
      gload16(W + (size_t)(n0 + row) * K + t * 32 + col,
              (char*)Bls[t & 1] + wave * 1024 + j * 4096);
    }
  };

  issue(0);                                        // 3 outstanding
  for (int t = 0; t < KT; ++t) {
    if (t + 1 < KT) {
      issue(t + 1);                                // 6 outstanding
      asm volatile("s_waitcnt vmcnt(3)" ::: "memory");  // tile t landed
    } else {
      asm volatile("s_waitcnt vmcnt(0)" ::: "memory");
    }
    BARRIER();
    const u16* Ab = Als[t & 1];
    const u16* Bb = Bls[t & 1];
    bf16x8 af[2], bfr[4];
#pragma unroll
    for (int m = 0; m < 2; ++m) af[m]  = *(const bf16x8*)&Ab[(wr * 32 + m * 16 + llo) * 32 + lhi * 8];
#pragma unroll
    for (int n = 0; n < 4; ++n) bfr[n] = *(const bf16x8*)&Bb[(wc * 64 + n * 16 + llo) * 32 + lhi * 8];
#pragma unroll
    for (int m = 0; m < 2; ++m)
#pragma unroll
      for (int n = 0; n < 4; ++n)
        acc[m][n] = __builtin_amdgcn_mfma_f32_16x16x32_bf16(af[m], bfr[n], acc[m][n], 0, 0, 0);
    BARRIER();
  }

#pragma unroll
  for (int n = 0; n < 4; ++n) {
    const int gcol = n0 + wc * 64 + n * 16 + llo;
    const float bv = bias[gcol];
#pragma unroll
    for (int m = 0; m < 2; ++m) {
      const int rowb = m0 + wr * 32 + m * 16 + lhi * 4;
#pragma unroll
      for (int r = 0; r < 4; ++r)
        Cf[(size_t)(rowb + r) * N + gcol] = acc[m][n][r] + bv;
    }
  }
}

// Flash attention fwd, ROUND-17: intra-block kv-split. 512 threads = 8 waves:
// wave = (qsub 0-3, half 0-1); each wave 32 q-rows x 16 kv-tiles. Per-half
// double-buffered K/V^T (64 KB), depth-1 counted vmcnt; serial qk->sm->pv per
// tile (4 waves/SIMD cross-wave overlap). Position-wise flash-combine epilogue
// (exact f32). All within-tile addressing/softmax math = 6-round-verified code.
__global__ __launch_bounds__(512, 4)
void attn_fwd(const u16* __restrict__ Qb, const u16* __restrict__ Kb,
              const u16* __restrict__ VbT, u16* __restrict__ Obf) {
  __shared__ __align__(16) u16 Kls[4][KVB * HD];   // [half*2+buf] 32KB
  __shared__ __align__(16) u16 Vls[4][HD * KVB];   // 32KB
  __shared__ __align__(16) float sBc[4][32], sC1[4][32], sM[4][32], sL[4][32];
  const int tid  = threadIdx.x;
  const int wave = tid >> 6, lane = tid & 63;
  const int qsub = wave & 3, half = wave >> 2;
  const int q    = lane & 31, hi = lane >> 5;
  const int bid  = blockIdx.x;               // 0..511
  const int g    = bid >> 3;                 // 0..63
  const int bh   = (bid & 7) * 4 + (g >> 4); // 0..31
  const int q0   = (g & 15) * QBLK;
  const size_t base  = (size_t)bh * S_ * HD;
  const size_t basev = (size_t)bh * HD * S_;

  const int qrow = q0 + qsub * 32 + q;
  bf16x8 qf[4];
#pragma unroll
  for (int c = 0; c < 4; ++c)
    qf[c] = *(const bf16x8*)&Qb[base + (size_t)qrow * HD + c * 16 + hi * 8];

  // staging: group (tid>>8) == half stages & consumes its own tile stream
  const int tid8 = tid & 255;
  const int srow = tid8 >> 3;                      // 0..31 (+32 on pass 1)
  const int xs   = (tid8 & 7) ^ (srow & 7);
  const u16* kSrc = Kb  + base  + (size_t)(half * NTS * KVB + srow) * HD + xs * 8;
  const u16* vSrc = VbT + basev + (size_t)srow * S_ + half * NTS * KVB + xs * 8;
  const int ldsW = qsub * 1024;

  const int gq = 16 * (q >> 4) + 8 * ((q >> 2) & 1) + (q & 3) + 4 * ((q >> 3) & 1);
  int offK[2][4], offV[2][4];
#pragma unroll
  for (int b = 0; b < 2; ++b)
#pragma unroll
    for (int c = 0; c < 4; ++c) {
      offK[b][c] = (b * 32 + gq) * 128 + (((c * 2 + hi) ^ (gq & 7)) << 4);
      offV[b][c] = (b * 32 + q)  * 128 + (((c * 2 + hi) ^ (q  & 7)) << 4);
    }

  f32x16 o0, o1, z16;
#pragma unroll
  for (int r = 0; r < 16; ++r) { o0[r] = 0.f; o1[r] = 0.f; z16[r] = 0.f; }
  float m_run = -1e30f, lsum = 0.f;

  auto issue = [&](int t) {                        // local tile 0..15
#pragma unroll
    for (int p = 0; p < 2; ++p) {
      gload16(kSrc + (size_t)t * KVB * HD + (size_t)p * 32 * HD,
              (char*)Kls[half * 2 + (t & 1)] + p * 4096 + ldsW);
      gload16(vSrc + t * KVB + (size_t)p * 32 * S_,
              (char*)Vls[half * 2 + (t & 1)] + p * 4096 + ldsW);
    }
  };

  auto compute = [&](int t) {
    const char* Kt = (const char*)Kls[half * 2 + (t & 1)];
    const char* Vt = (const char*)Vls[half * 2 + (t & 1)];

    // ---- QK^T (first MFMA uses z16 C-in) ----
    f32x16 s0, s1;
    {
      bf16x8 k0 = *(const bf16x8*)(Kt + offK[0][0]);
      bf16x8 k1 = *(const bf16x8*)(Kt + offK[1][0]);
      s0 = __builtin_amdgcn_mfma_f32_32x32x16_bf16(k0, qf[0], z16, 0, 0, 0);
      s1 = __builtin_amdgcn_mfma_f32_32x32x16_bf16(k1, qf[0], z16, 0, 0, 0);
    }
#pragma unroll
    for (int c = 1; c < 4; ++c) {
      bf16x8 k0 = *(const bf16x8*)(Kt + offK[0][c]);
      bf16x8 k1 = *(const bf16x8*)(Kt + offK[1][c]);
      s0 = __builtin_amdgcn_mfma_f32_32x32x16_bf16(k0, qf[c], s0, 0, 0, 0);
      s1 = __builtin_amdgcn_mfma_f32_32x32x16_bf16(k1, qf[c], s1, 0, 0, 0);
    }

    // ---- online softmax ----
    float tm[16];
#pragma unroll
    for (int r = 0; r < 16; ++r) tm[r] = fmaxf(s0[r], s1[r]);
#pragma unroll
    for (int st = 8; st >= 1; st >>= 1)
#pragma unroll
      for (int i = 0; i < 16; ++i) if (i < st) tm[i] = fmaxf(tm[i], tm[i + st]);
    const float pm = fmaxf(tm[0], __shfl_xor(tm[0], 32));

    if (__any(pm > m_run + 10.0f)) {
      const float mnew  = fmaxf(m_run, pm);
      const float alpha = exp2f(m_run - mnew);
      sBc[wave & 3][q] = alpha;   // per-wave slot would clash across halves!
      // NOTE: halves share qsub -> use a per-half offset via sC1 for half 1
      // (see below) -- instead we use distinct arrays per half:
      // half 0 -> sBc, half 1 -> sC1 (both [4][32], only used transiently here)
      float* bcast = (half == 0) ? &sBc[qsub][0] : &sC1[qsub][0];
      bcast[q] = alpha;
      asm volatile("s_waitcnt lgkmcnt(0)" ::: "memory");
      f32x4 av[4];
#pragma unroll
      for (int gg = 0; gg < 4; ++gg) av[gg] = *(const f32x4*)&bcast[hi * 4 + gg * 8];
#pragma unroll
      for (int r = 0; r < 16; ++r) {
        const float f = av[r >> 2][r & 3];
        o0[r] *= f; o1[r] *= f;
      }
      lsum *= alpha;
      m_run = mnew;
    }

    float t0 = 0.f, t1 = 0.f, t2 = 0.f, t3 = 0.f;
    u32 dw0[8], dw1[8];
#pragma unroll
    for (int j = 0; j < 8; ++j) {
      const float a0 = exp2f(s0[2 * j] - m_run), a1 = exp2f(s0[2 * j + 1] - m_run);
      const float b0 = exp2f(s1[2 * j] - m_run), b1 = exp2f(s1[2 * j + 1] - m_run);
      t0 += a0; t1 += a1; t2 += b0; t3 += b1;
      dw0[j] = cvtpk(a0, a1);
      dw1[j] = cvtpk(b0, b1);
    }
    float ts = (t0 + t1) + (t2 + t3);
    ts += __shfl_xor(ts, 32);
    lsum += ts;

    // ---- PV ----
#pragma unroll
    for (int c = 0; c < 4; ++c) {
      union { u32 u[4]; bf16x8 v; } P;
      if (c == 0)      { P.u[0] = dw0[0]; P.u[1] = dw0[1]; P.u[2] = dw0[2]; P.u[3] = dw0[3]; }
      else if (c == 1) { P.u[0] = dw0[4]; P.u[1] = dw0[5]; P.u[2] = dw0[6]; P.u[3] = dw0[7]; }
      else if (c == 2) { P.u[0] = dw1[0]; P.u[1] = dw1[1]; P.u[2] = dw1[2]; P.u[3] = dw1[3]; }
      else             { P.u[0] = dw1[4]; P.u[1] = dw1[5]; P.u[2] = dw1[6]; P.u[3] = dw1[7]; }
      bf16x8 v0 = *(const bf16x8*)(Vt + offV[0][c]);
      bf16x8 v1 = *(const bf16x8*)(Vt + offV[1][c]);
      o0 = __builtin_amdgcn_mfma_f32_32x32x16_bf16(P.v, v0, o0, 0, 0, 0);
      o1 = __builtin_amdgcn_mfma_f32_32x32x16_bf16(P.v, v1, o1, 0, 0, 0);
    }
  };

  issue(0);                                        // 4 outstanding
  for (int t = 0; t < NTS; ++t) {
    if (t + 1 < NTS) {
      issue(t + 1);                                // 8 outstanding
      asm volatile("s_waitcnt vmcnt(4)" ::: "memory");  // tile t landed
    } else {
      asm volatile("s_waitcnt vmcnt(0)" ::: "memory");
    }
    BARRIER();
    compute(t);
    BARRIER();                                     // buf (t&1) free for reuse
  }

  // ==== flash-combine across halves (position-wise, exact f32) ====
  BARRIER();                                       // all K/V LDS reads done
  float* X = (float*)Kls;                          // 8192 floats (32KB)
  const int bx = (qsub * 64 + lane) * 32;
  if (half == 1) {
#pragma unroll
    for (int j = 0; j < 4; ++j)
      *(f32x4*)&X[bx + ((j ^ (lane & 7)) << 2)] =
          f32x4{o0[4 * j], o0[4 * j + 1], o0[4 * j + 2], o0[4 * j + 3]};
#pragma unroll
    for (int j = 0; j < 4; ++j)
      *(f32x4*)&X[bx + (((j + 4) ^ (lane & 7)) << 2)] =
          f32x4{o1[4 * j], o1[4 * j + 1], o1[4 * j + 2], o1[4 * j + 3]};
    sM[qsub][q] = m_run;
    sL[qsub][q] = lsum;
  }
  asm volatile("s_waitcnt lgkmcnt(0)" ::: "memory");  // writers drained
  BARRIER();
  if (half == 0) {
    const float m1 = sM[qsub][q], l1 = sL[qsub][q];
    const float M  = fmaxf(m_run, m1);
    const float a0 = exp2f(m_run - M), a1 = exp2f(m1 - M);
    const float inv = 1.0f / (a0 * lsum + a1 * l1);
    sBc[qsub][q] = a0 * inv;
    sC1[qsub][q] = a1 * inv;
    asm volatile("s_waitcnt lgkmcnt(0)" ::: "memory");
    f32x4 c0v[4], c1v[4], p0[4], p1[4];
#pragma unroll
    for (int gg = 0; gg < 4; ++gg) {
      c0v[gg] = *(const f32x4*)&sBc[qsub][hi * 4 + gg * 8];
      c1v[gg] = *(const f32x4*)&sC1[qsub][hi * 4 + gg * 8];
      p0[gg]  = *(const f32x4*)&X[bx + ((gg ^ (lane & 7)) << 2)];
      p1[gg]  = *(const f32x4*)&X[bx + (((gg + 4) ^ (lane & 7)) << 2)];
    }
    const int b = bh >> 4, h = bh & 15;
#pragma unroll
    for (int r = 0; r < 16; ++r) {
      const float c0 = c0v[r >> 2][r & 3], c1 = c1v[r >> 2][r & 3];
      const int qg = q0 + qsub * 32 + (r & 3) + 8 * (r >> 2) + 4 * hi;
      u16* dst = Obf + ((size_t)(b * S_ + qg) * NH + h) * HD;
      dst[q]      = f2bf(o0[r] * c0 + p0[r >> 2][r & 3] * c1);
      dst[32 + q] = f2bf(o1[r] * c0 + p1[r >> 2][r & 3] * c1);
    }
  }
}

extern "C" void kernel_launch(void* const* d_in, const int* in_sizes, int n_in,
                              void* d_out, int out_size, void* d_ws, size_t ws_size,
                              hipStream_t stream) {
  const float* x     = (const float*)d_in[0];
  const float* qkv_w = (const float*)d_in[1];
  const float* qkv_b = (const float*)d_in[2];
  const float* o_w   = (const float*)d_in[3];
  const float* o_b   = (const float*)d_in[4];
  float* out = (float*)d_out;

  char* ws = (char*)d_ws;
  u16* xbf  = (u16*)(ws);                     // 8 MB; later aliased as attn output
  u16* wqkv = (u16*)(ws + (8u  << 20));       // 6 MB
  u16* wo   = (u16*)(ws + (14u << 20));       // 2 MB
  u16* Qb   = (u16*)(ws + (16u << 20));       // 8 MB  [B,H,S,d]
  u16* Kb   = (u16*)(ws + (24u << 20));       // 8 MB  [B,H,S,d]
  u16* VbT  = (u16*)(ws + (32u << 20));       // 8 MB  [B,H,d,S]
  u16* atnb = xbf;                            // [B,S,H,d] bf16 (x_bf dead by then)

  cast_all<<<8192, 256, 0, stream>>>(x, qkv_w, o_w, xbf, wqkv, wo);

  gemm_qkv<<<768, 256, 0, stream>>>(xbf, wqkv, qkv_b, Qb, Kb, VbT);

  attn_fwd<<<512, 512, 0, stream>>>(Qb, Kb, VbT, atnb);

  gemm_out_m64<<<512, 256, 0, stream>>>(atnb, wo, o_b, out, MROWS, EMB, EMB);
}

// Round 18
// 130.452 us; speedup vs baseline: 1.0026x; 1.0026x over previous
//
#include <hip/hip_runtime.h>
#include <hip/hip_bf16.h>

#define B_    2
#define S_    2048
#define DIN   1024
#define EMB   1024
#define NH    16
#define HD    64
#define N3    3072
#define MROWS 4096   // B_*S_
#define KVB   64
#define QBLK  128
#define NT    (S_ / KVB)   // 32 kv tiles

typedef short bf16x8 __attribute__((ext_vector_type(8)));
typedef float f32x4  __attribute__((ext_vector_type(4)));
typedef float f32x16 __attribute__((ext_vector_type(16)));
typedef unsigned short u16;
typedef u16 u16x8 __attribute__((ext_vector_type(8)));
typedef u16 u16x4 __attribute__((ext_vector_type(4)));
typedef unsigned int u32;

__device__ __forceinline__ u16 f2bf(float f) {
  union { float f; unsigned u; } x; x.f = f;
  unsigned r = x.u + 0x7fffu + ((x.u >> 16) & 1u);
  return (u16)(r >> 16);
}

__device__ __forceinline__ u32 cvtpk(float lo, float hi) {
  u32 r;
  asm("v_cvt_pk_bf16_f32 %0, %1, %2" : "=v"(r) : "v"(lo), "v"(hi));
  return r;
}

__device__ __forceinline__ void gload16(const void* g, void* l) {
  __builtin_amdgcn_global_load_lds(
      (const __attribute__((address_space(1))) unsigned int*)g,
      (__attribute__((address_space(3))) unsigned int*)l, 16, 0, 0);
}

#define BARRIER() do { asm volatile("" ::: "memory"); \
                       __builtin_amdgcn_s_barrier();  \
                       asm volatile("" ::: "memory"); } while (0)

// one fused cast: x (1048576 float4) + qkv_w (786432) + o_w (262144)
__global__ __launch_bounds__(256)
void cast_all(const float* __restrict__ x, const float* __restrict__ w1,
              const float* __restrict__ w2, u16* __restrict__ ox,
              u16* __restrict__ ow1, u16* __restrict__ ow2) {
  const int i = blockIdx.x * 256 + threadIdx.x;   // 0..2097151
  const float* src; u16* dst; int off;
  if (i < 1048576)              { src = x;  dst = ox;  off = i; }
  else if (i < 1048576 + 786432){ src = w1; dst = ow1; off = i - 1048576; }
  else                          { src = w2; dst = ow2; off = i - 1835008; }
  const float4 v = ((const float4*)src)[off];
  u16x4 o;
  o[0] = f2bf(v.x); o[1] = f2bf(v.y); o[2] = f2bf(v.z); o[3] = f2bf(v.w);
  ((u16x4*)dst)[off] = o;
}

// QKV projection GEMM (round-16 verified): 128x128, BK=32, dbuf LDS, depth-1
// counted-vmcnt prefetch, XCD-grouped n-outer block decode.
__global__ __launch_bounds__(256)
void gemm_qkv(const u16* __restrict__ A, const u16* __restrict__ W,
              const float* __restrict__ bias,
              u16* __restrict__ Qb, u16* __restrict__ Kb, u16* __restrict__ VbT) {
  __shared__ u16 Als[2][128 * 32];
  __shared__ u16 Bls[2][128 * 32];
  const int K = DIN;
  const int tid  = threadIdx.x;
  const int wave = tid >> 6, lane = tid & 63;
  const int lhi  = lane >> 4, llo = lane & 15;
  const int wr   = wave >> 1, wc = wave & 1;
  const int bid  = blockIdx.x;               // 0..767
  const int xcd  = bid & 7, i = bid >> 3;    // i: 0..95
  const int m0   = (xcd * 4 + (i & 3)) * 128;
  const int n0   = (i >> 2) * 128;
  const int KT   = K >> 5;

  f32x4 acc[4][4];
#pragma unroll
  for (int m = 0; m < 4; ++m)
#pragma unroll
    for (int n = 0; n < 4; ++n) acc[m][n] = f32x4{0.f, 0.f, 0.f, 0.f};

  auto issue = [&](int t) {
#pragma unroll
    for (int j = 0; j < 2; ++j) {
      const int e   = (tid + j * 256) * 8;   // element index in [128][32] tile
      const int row = e >> 5, col = e & 31;
      gload16(A + (size_t)(m0 + row) * K + t * 32 + col,
              (char*)Als[t & 1] + wave * 1024 + j * 4096);
      gload16(W + (size_t)(n0 + row) * K + t * 32 + col,
              (char*)Bls[t & 1] + wave * 1024 + j * 4096);
    }
  };

  issue(0);                                        // 4 outstanding
  for (int t = 0; t < KT; ++t) {
    if (t + 1 < KT) {
      issue(t + 1);                                // 8 outstanding
      asm volatile("s_waitcnt vmcnt(4)" ::: "memory");  // tile t landed
    } else {
      asm volatile("s_waitcnt vmcnt(0)" ::: "memory");
    }
    BARRIER();
    const u16* Ab = Als[t & 1];
    const u16* Bb = Bls[t & 1];
    bf16x8 af[4], bfr[4];
#pragma unroll
    for (int m = 0; m < 4; ++m) af[m]  = *(const bf16x8*)&Ab[(wr * 64 + m * 16 + llo) * 32 + lhi * 8];
#pragma unroll
    for (int n = 0; n < 4; ++n) bfr[n] = *(const bf16x8*)&Bb[(wc * 64 + n * 16 + llo) * 32 + lhi * 8];
#pragma unroll
    for (int m = 0; m < 4; ++m)
#pragma unroll
      for (int n = 0; n < 4; ++n)
        acc[m][n] = __builtin_amdgcn_mfma_f32_16x16x32_bf16(af[m], bfr[n], acc[m][n], 0, 0, 0);
    BARRIER();
  }

#pragma unroll
  for (int n = 0; n < 4; ++n) {
    const int colb = n0 + wc * 64 + n * 16;  // 16-aligned; within one 64-col section
    const int gcol = colb + llo;
    const float bv = bias[gcol];
    const int h   = colb / 192;
    const int rr  = colb - h * 192;
    const int sec = rr >> 6;                 // 0:Q 1:K 2:V
    const int d   = (rr & 63) + llo;
#pragma unroll
    for (int m = 0; m < 4; ++m) {
      const int rowb = m0 + wr * 64 + m * 16 + lhi * 4;
      const int b = rowb >> 11, s0 = rowb & 2047;
      if (sec == 2) {
        u16x4 vv;
#pragma unroll
        for (int r = 0; r < 4; ++r) vv[r] = f2bf(acc[m][n][r] + bv);
        *(u16x4*)&VbT[((size_t)(b * NH + h) * HD + d) * S_ + s0] = vv;
      } else {
        u16* dst = (sec == 0) ? Qb : Kb;
        const float scl = (sec == 0) ? 0.18033688f : 1.0f;  // 0.125*log2(e)
#pragma unroll
        for (int r = 0; r < 4; ++r)
          dst[(((size_t)(b * NH + h) * S_ + s0 + r) << 6) + d] = f2bf((acc[m][n][r] + bv) * scl);
      }
    }
  }
}

// Out-projection GEMM (round-16 verified): M-split 64x128, XCD-grouped decode.
__global__ __launch_bounds__(256)
void gemm_out_m64(const u16* __restrict__ A, const u16* __restrict__ W,
                  const float* __restrict__ bias, float* __restrict__ Cf,
                  int M, int N, int K) {
  __shared__ u16 Als[2][64 * 32];
  __shared__ u16 Bls[2][128 * 32];
  const int tid  = threadIdx.x;
  const int wave = tid >> 6, lane = tid & 63;
  const int lhi  = lane >> 4, llo = lane & 15;
  const int wr   = wave >> 1, wc = wave & 1;
  const int bid  = blockIdx.x;               // 0..511
  const int xcd  = bid & 7, i = bid >> 3;    // i: 0..63
  const int m0   = (xcd * 8 + (i & 7)) * 64;
  const int n0   = (i >> 3) * 128;
  const int KT   = K >> 5;

  f32x4 acc[2][4];
#pragma unroll
  for (int m = 0; m < 2; ++m)
#pragma unroll
    for (int n = 0; n < 4; ++n) acc[m][n] = f32x4{0.f, 0.f, 0.f, 0.f};

  auto issue = [&](int t) {
    {
      const int row = tid >> 2, col = (tid & 3) * 8;
      gload16(A + (size_t)(m0 + row) * K + t * 32 + col,
              (char*)Als[t & 1] + wave * 1024);
    }
#pragma unroll
    for (int j = 0; j < 2; ++j) {
      const int e   = (tid + j * 256) * 8;
      const int row = e >> 5, col = e & 31;
      gload16(W + (size_t)(n0 + row) * K + t * 32 + col,
              (char*)Bls[t & 1] + wave * 1024 + j * 4096);
    }
  };

  issue(0);                                        // 3 outstanding
  for (int t = 0; t < KT; ++t) {
    if (t + 1 < KT) {
      issue(t + 1);                                // 6 outstanding
      asm volatile("s_waitcnt vmcnt(3)" ::: "memory");  // tile t landed
    } else {
      asm volatile("s_waitcnt vmcnt(0)" ::: "memory");
    }
    BARRIER();
    const u16* Ab = Als[t & 1];
    const u16* Bb = Bls[t & 1];
    bf16x8 af[2], bfr[4];
#pragma unroll
    for (int m = 0; m < 2; ++m) af[m]  = *(const bf16x8*)&Ab[(wr * 32 + m * 16 + llo) * 32 + lhi * 8];
#pragma unroll
    for (int n = 0; n < 4; ++n) bfr[n] = *(const bf16x8*)&Bb[(wc * 64 + n * 16 + llo) * 32 + lhi * 8];
#pragma unroll
    for (int m = 0; m < 2; ++m)
#pragma unroll
      for (int n = 0; n < 4; ++n)
        acc[m][n] = __builtin_amdgcn_mfma_f32_16x16x32_bf16(af[m], bfr[n], acc[m][n], 0, 0, 0);
    BARRIER();
  }

#pragma unroll
  for (int n = 0; n < 4; ++n) {
    const int gcol = n0 + wc * 64 + n * 16 + llo;
    const float bv = bias[gcol];
#pragma unroll
    for (int m = 0; m < 2; ++m) {
      const int rowb = m0 + wr * 32 + m * 16 + lhi * 4;
#pragma unroll
      for (int r = 0; r < 4; ++r)
        Cf[(size_t)(rowb + r) * N + gcol] = acc[m][n][r] + bv;
    }
  }
}

// Flash attention fwd (round-16 base + MFMA row-sum): 32x32x16 MFMA, permuted
// K-row reads, defer-max, quad-buffered K/V^T, counted vmcnt, even/odd software
// pipeline, XCD-grouped grid decode. ROUND-18: softmax row-sum moved to the
// MFMA pipe via lacc = mfma(P, ones, lacc) -- D[q-row, col] = sum_kv P is
// column-independent (layout-proof); removes 16 adds + 1 ds_bpermute per tile
// from the serial VALU chain and the finalize LDS broadcast of 1/lsum.
__global__ __launch_bounds__(256, 2)
void attn_fwd(const u16* __restrict__ Qb, const u16* __restrict__ Kb,
              const u16* __restrict__ VbT, u16* __restrict__ Obf) {
  __shared__ __align__(16) u16 Kls[4][KVB * HD];
  __shared__ __align__(16) u16 Vls[4][HD * KVB];
  __shared__ __align__(16) float sBc[4][32];
  const int tid  = threadIdx.x;
  const int wave = tid >> 6, lane = tid & 63;
  const int q    = lane & 31, hi = lane >> 5;
  const int bid  = blockIdx.x;               // 0..511
  const int g    = bid >> 3;                 // 0..63
  const int bh   = (bid & 7) * 4 + (g >> 4); // 0..31
  const int q0   = (g & 15) * QBLK;
  const size_t base  = (size_t)bh * S_ * HD;
  const size_t basev = (size_t)bh * HD * S_;

  const int qrow = q0 + wave * 32 + q;
  bf16x8 qf[4];
#pragma unroll
  for (int c = 0; c < 4; ++c)
    qf[c] = *(const bf16x8*)&Qb[base + (size_t)qrow * HD + c * 16 + hi * 8];

  const int srow = tid >> 3;
  const int xs   = (tid & 7) ^ (srow & 7);
  const u16* kSrc = Kb  + base  + (size_t)srow * HD + xs * 8;
  const u16* vSrc = VbT + basev + (size_t)srow * S_ + xs * 8;
  const int ldsW = wave * 1024;

  const int gq = 16 * (q >> 4) + 8 * ((q >> 2) & 1) + (q & 3) + 4 * ((q >> 3) & 1);
  int offK[2][4], offV[2][4];
#pragma unroll
  for (int b = 0; b < 2; ++b)
#pragma unroll
    for (int c = 0; c < 4; ++c) {
      offK[b][c] = (b * 32 + gq) * 128 + (((c * 2 + hi) ^ (gq & 7)) << 4);
      offV[b][c] = (b * 32 + q)  * 128 + (((c * 2 + hi) ^ (q  & 7)) << 4);
    }

  f32x16 o0, o1, z16, lacc;
#pragma unroll
  for (int r = 0; r < 16; ++r) { o0[r] = 0.f; o1[r] = 0.f; z16[r] = 0.f; lacc[r] = 0.f; }
  bf16x8 onesf;
#pragma unroll
  for (int r = 0; r < 8; ++r) onesf[r] = (short)0x3F80;   // bf16 1.0
  float m_run = -1e30f;

  auto issue = [&](int t) {
#pragma unroll
    for (int p = 0; p < 2; ++p) {
      gload16(kSrc + (size_t)t * KVB * HD + (size_t)p * 32 * HD,
              (char*)Kls[t & 3] + p * 4096 + ldsW);
      gload16(vSrc + t * KVB + (size_t)p * 32 * S_,
              (char*)Vls[t & 3] + p * 4096 + ldsW);
    }
  };

  auto qk = [&](int t, f32x16& s0, f32x16& s1) {
    const char* Kt = (const char*)Kls[t & 3];
    {
      bf16x8 k0 = *(const bf16x8*)(Kt + offK[0][0]);
      bf16x8 k1 = *(const bf16x8*)(Kt + offK[1][0]);
      s0 = __builtin_amdgcn_mfma_f32_32x32x16_bf16(k0, qf[0], z16, 0, 0, 0);
      s1 = __builtin_amdgcn_mfma_f32_32x32x16_bf16(k1, qf[0], z16, 0, 0, 0);
    }
#pragma unroll
    for (int c = 1; c < 4; ++c) {
      bf16x8 k0 = *(const bf16x8*)(Kt + offK[0][c]);
      bf16x8 k1 = *(const bf16x8*)(Kt + offK[1][c]);
      s0 = __builtin_amdgcn_mfma_f32_32x32x16_bf16(k0, qf[c], s0, 0, 0, 0);
      s1 = __builtin_amdgcn_mfma_f32_32x32x16_bf16(k1, qf[c], s1, 0, 0, 0);
    }
  };

  // online softmax: updates m_run, rescales o/lacc on rare max growth,
  // emits packed P (row-sum accumulation happens in pv via ones-MFMA)
  auto sm = [&](f32x16& s0, f32x16& s1, u32 (&dw0)[8], u32 (&dw1)[8]) {
    float tm[16];
#pragma unroll
    for (int r = 0; r < 16; ++r) tm[r] = fmaxf(s0[r], s1[r]);
#pragma unroll
    for (int st = 8; st >= 1; st >>= 1)
#pragma unroll
      for (int i = 0; i < 16; ++i) if (i < st) tm[i] = fmaxf(tm[i], tm[i + st]);
    const float pm = fmaxf(tm[0], __shfl_xor(tm[0], 32));

    if (__any(pm > m_run + 10.0f)) {
      const float mnew  = fmaxf(m_run, pm);
      const float alpha = exp2f(m_run - mnew);
      sBc[wave][q] = alpha;
      asm volatile("s_waitcnt lgkmcnt(0)" ::: "memory");
      f32x4 av[4];
#pragma unroll
      for (int gg = 0; gg < 4; ++gg) av[gg] = *(const f32x4*)&sBc[wave][hi * 4 + gg * 8];
#pragma unroll
      for (int r = 0; r < 16; ++r) {
        const float f = av[r >> 2][r & 3];
        o0[r] *= f; o1[r] *= f; lacc[r] *= f;
      }
      m_run = mnew;
    }

#pragma unroll
    for (int j = 0; j < 8; ++j) {
      const float a0 = exp2f(s0[2 * j] - m_run), a1 = exp2f(s0[2 * j + 1] - m_run);
      const float b0 = exp2f(s1[2 * j] - m_run), b1 = exp2f(s1[2 * j + 1] - m_run);
      dw0[j] = cvtpk(a0, a1);
      dw1[j] = cvtpk(b0, b1);
    }
  };

  // PV: O += P @ V; lacc += P @ ones (row-sum on the MFMA pipe)
  auto pv = [&](int t, u32 (&dw0)[8], u32 (&dw1)[8]) {
    const char* Vt = (const char*)Vls[t & 3];
#pragma unroll
    for (int c = 0; c < 4; ++c) {
      union { u32 u[4]; bf16x8 v; } P;
      if (c == 0)      { P.u[0] = dw0[0]; P.u[1] = dw0[1]; P.u[2] = dw0[2]; P.u[3] = dw0[3]; }
      else if (c == 1) { P.u[0] = dw0[4]; P.u[1] = dw0[5]; P.u[2] = dw0[6]; P.u[3] = dw0[7]; }
      else if (c == 2) { P.u[0] = dw1[0]; P.u[1] = dw1[1]; P.u[2] = dw1[2]; P.u[3] = dw1[3]; }
      else             { P.u[0] = dw1[4]; P.u[1] = dw1[5]; P.u[2] = dw1[6]; P.u[3] = dw1[7]; }
      bf16x8 v0 = *(const bf16x8*)(Vt + offV[0][c]);
      bf16x8 v1 = *(const bf16x8*)(Vt + offV[1][c]);
      o0   = __builtin_amdgcn_mfma_f32_32x32x16_bf16(P.v, v0,    o0,   0, 0, 0);
      o1   = __builtin_amdgcn_mfma_f32_32x32x16_bf16(P.v, v1,    o1,   0, 0, 0);
      lacc = __builtin_amdgcn_mfma_f32_32x32x16_bf16(P.v, onesf, lacc, 0, 0, 0);
    }
  };

  f32x16 sE0, sE1, sO0, sO1;
  u32 dwE0[8], dwE1[8], dwO0[8], dwO1[8];

  issue(0); issue(1);
  for (int p = 0; p < NT / 2 - 1; ++p) {
    issue(2 * p + 2); issue(2 * p + 3);
    asm volatile("s_waitcnt vmcnt(8)" ::: "memory");  // pair p landed
    BARRIER();
    qk(2 * p,     sE0, sE1);          // MFMA
    qk(2 * p + 1, sO0, sO1);          // MFMA, independent -> overlaps sm(e)
    sm(sE0, sE1, dwE0, dwE1);         // VALU
    pv(2 * p,     dwE0, dwE1);        // MFMA -> overlaps sm(o) exp/pack
    sm(sO0, sO1, dwO0, dwO1);         // VALU
    pv(2 * p + 1, dwO0, dwO1);        // MFMA
    BARRIER();                        // pair p bufs free for reuse
  }
  asm volatile("s_waitcnt vmcnt(0)" ::: "memory");
  BARRIER();
  qk(NT - 2, sE0, sE1);
  qk(NT - 1, sO0, sO1);
  sm(sE0, sE1, dwE0, dwE1);
  pv(NT - 2, dwE0, dwE1);
  sm(sO0, sO1, dwO0, dwO1);
  pv(NT - 1, dwO0, dwO1);

  // ---- finalize: per-row 1/lsum directly from lacc (no LDS broadcast) ----
  const int b = bh >> 4, h = bh & 15;
#pragma unroll
  for (int r = 0; r < 16; ++r) {
    const int qg = q0 + wave * 32 + (r & 3) + 8 * (r >> 2) + 4 * hi;
    const float f = 1.0f / lacc[r];
    u16* dst = Obf + ((size_t)(b * S_ + qg) * NH + h) * HD;
    dst[q]      = f2bf(o0[r] * f);
    dst[32 + q] = f2bf(o1[r] * f);
  }
}

extern "C" void kernel_launch(void* const* d_in, const int* in_sizes, int n_in,
                              void* d_out, int out_size, void* d_ws, size_t ws_size,
                              hipStream_t stream) {
  const float* x     = (const float*)d_in[0];
  const float* qkv_w = (const float*)d_in[1];
  const float* qkv_b = (const float*)d_in[2];
  const float* o_w   = (const float*)d_in[3];
  const float* o_b   = (const float*)d_in[4];
  float* out = (float*)d_out;

  char* ws = (char*)d_ws;
  u16* xbf  = (u16*)(ws);                     // 8 MB; later aliased as attn output
  u16* wqkv = (u16*)(ws + (8u  << 20));       // 6 MB
  u16* wo   = (u16*)(ws + (14u << 20));       // 2 MB
  u16* Qb   = (u16*)(ws + (16u << 20));       // 8 MB  [B,H,S,d]
  u16* Kb   = (u16*)(ws + (24u << 20));       // 8 MB  [B,H,S,d]
  u16* VbT  = (u16*)(ws + (32u << 20));       // 8 MB  [B,H,d,S]
  u16* atnb = xbf;                            // [B,S,H,d] bf16 (x_bf dead by then)

  cast_all<<<8192, 256, 0, stream>>>(x, qkv_w, o_w, xbf, wqkv, wo);

  gemm_qkv<<<768, 256, 0, stream>>>(xbf, wqkv, qkv_b, Qb, Kb, VbT);

  attn_fwd<<<512, 256, 0, stream>>>(Qb, Kb, VbT, atnb);

  gemm_out_m64<<<512, 256, 0, stream>>>(atnb, wo, o_b, out, MROWS, EMB, EMB);
}

// Round 19
// 128.800 us; speedup vs baseline: 1.0154x; 1.0128x over previous
//
#include <hip/hip_runtime.h>
#include <hip/hip_bf16.h>

#define B_    2
#define S_    2048
#define DIN   1024
#define EMB   1024
#define NH    16
#define HD    64
#define N3    3072
#define MROWS 4096   // B_*S_
#define KVB   64
#define QBLK  128
#define NT    (S_ / KVB)   // 32 kv tiles

typedef short bf16x8 __attribute__((ext_vector_type(8)));
typedef float f32x4  __attribute__((ext_vector_type(4)));
typedef float f32x16 __attribute__((ext_vector_type(16)));
typedef unsigned short u16;
typedef u16 u16x8 __attribute__((ext_vector_type(8)));
typedef u16 u16x4 __attribute__((ext_vector_type(4)));
typedef unsigned int u32;

__device__ __forceinline__ u16 f2bf(float f) {
  union { float f; unsigned u; } x; x.f = f;
  unsigned r = x.u + 0x7fffu + ((x.u >> 16) & 1u);
  return (u16)(r >> 16);
}

__device__ __forceinline__ u32 cvtpk(float lo, float hi) {
  u32 r;
  asm("v_cvt_pk_bf16_f32 %0, %1, %2" : "=v"(r) : "v"(lo), "v"(hi));
  return r;
}

__device__ __forceinline__ void gload16(const void* g, void* l) {
  __builtin_amdgcn_global_load_lds(
      (const __attribute__((address_space(1))) unsigned int*)g,
      (__attribute__((address_space(3))) unsigned int*)l, 16, 0, 0);
}

#define BARRIER() do { asm volatile("" ::: "memory"); \
                       __builtin_amdgcn_s_barrier();  \
                       asm volatile("" ::: "memory"); } while (0)

// one fused cast: x (1048576 float4) + qkv_w (786432) + o_w (262144)
__global__ __launch_bounds__(256)
void cast_all(const float* __restrict__ x, const float* __restrict__ w1,
              const float* __restrict__ w2, u16* __restrict__ ox,
              u16* __restrict__ ow1, u16* __restrict__ ow2) {
  const int i = blockIdx.x * 256 + threadIdx.x;   // 0..2097151
  const float* src; u16* dst; int off;
  if (i < 1048576)              { src = x;  dst = ox;  off = i; }
  else if (i < 1048576 + 786432){ src = w1; dst = ow1; off = i - 1048576; }
  else                          { src = w2; dst = ow2; off = i - 1835008; }
  const float4 v = ((const float4*)src)[off];
  u16x4 o;
  o[0] = f2bf(v.x); o[1] = f2bf(v.y); o[2] = f2bf(v.z); o[3] = f2bf(v.w);
  ((u16x4*)dst)[off] = o;
}

// QKV projection GEMM (round-16 verified): 128x128, BK=32, dbuf LDS, depth-1
// counted-vmcnt prefetch, XCD-grouped n-outer block decode.
__global__ __launch_bounds__(256)
void gemm_qkv(const u16* __restrict__ A, const u16* __restrict__ W,
              const float* __restrict__ bias,
              u16* __restrict__ Qb, u16* __restrict__ Kb, u16* __restrict__ VbT) {
  __shared__ u16 Als[2][128 * 32];
  __shared__ u16 Bls[2][128 * 32];
  const int K = DIN;
  const int tid  = threadIdx.x;
  const int wave = tid >> 6, lane = tid & 63;
  const int lhi  = lane >> 4, llo = lane & 15;
  const int wr   = wave >> 1, wc = wave & 1;
  const int bid  = blockIdx.x;               // 0..767
  const int xcd  = bid & 7, i = bid >> 3;    // i: 0..95
  const int m0   = (xcd * 4 + (i & 3)) * 128;
  const int n0   = (i >> 2) * 128;
  const int KT   = K >> 5;

  f32x4 acc[4][4];
#pragma unroll
  for (int m = 0; m < 4; ++m)
#pragma unroll
    for (int n = 0; n < 4; ++n) acc[m][n] = f32x4{0.f, 0.f, 0.f, 0.f};

  auto issue = [&](int t) {
#pragma unroll
    for (int j = 0; j < 2; ++j) {
      const int e   = (tid + j * 256) * 8;   // element index in [128][32] tile
      const int row = e >> 5, col = e & 31;
      gload16(A + (size_t)(m0 + row) * K + t * 32 + col,
              (char*)Als[t & 1] + wave * 1024 + j * 4096);
      gload16(W + (size_t)(n0 + row) * K + t * 32 + col,
              (char*)Bls[t & 1] + wave * 1024 + j * 4096);
    }
  };

  issue(0);                                        // 4 outstanding
  for (int t = 0; t < KT; ++t) {
    if (t + 1 < KT) {
      issue(t + 1);                                // 8 outstanding
      asm volatile("s_waitcnt vmcnt(4)" ::: "memory");  // tile t landed
    } else {
      asm volatile("s_waitcnt vmcnt(0)" ::: "memory");
    }
    BARRIER();
    const u16* Ab = Als[t & 1];
    const u16* Bb = Bls[t & 1];
    bf16x8 af[4], bfr[4];
#pragma unroll
    for (int m = 0; m < 4; ++m) af[m]  = *(const bf16x8*)&Ab[(wr * 64 + m * 16 + llo) * 32 + lhi * 8];
#pragma unroll
    for (int n = 0; n < 4; ++n) bfr[n] = *(const bf16x8*)&Bb[(wc * 64 + n * 16 + llo) * 32 + lhi * 8];
#pragma unroll
    for (int m = 0; m < 4; ++m)
#pragma unroll
      for (int n = 0; n < 4; ++n)
        acc[m][n] = __builtin_amdgcn_mfma_f32_16x16x32_bf16(af[m], bfr[n], acc[m][n], 0, 0, 0);
    BARRIER();
  }

#pragma unroll
  for (int n = 0; n < 4; ++n) {
    const int colb = n0 + wc * 64 + n * 16;  // 16-aligned; within one 64-col section
    const int gcol = colb + llo;
    const float bv = bias[gcol];
    const int h   = colb / 192;
    const int rr  = colb - h * 192;
    const int sec = rr >> 6;                 // 0:Q 1:K 2:V
    const int d   = (rr & 63) + llo;
#pragma unroll
    for (int m = 0; m < 4; ++m) {
      const int rowb = m0 + wr * 64 + m * 16 + lhi * 4;
      const int b = rowb >> 11, s0 = rowb & 2047;
      if (sec == 2) {
        u16x4 vv;
#pragma unroll
        for (int r = 0; r < 4; ++r) vv[r] = f2bf(acc[m][n][r] + bv);
        *(u16x4*)&VbT[((size_t)(b * NH + h) * HD + d) * S_ + s0] = vv;
      } else {
        u16* dst = (sec == 0) ? Qb : Kb;
        const float scl = (sec == 0) ? 0.18033688f : 1.0f;  // 0.125*log2(e)
#pragma unroll
        for (int r = 0; r < 4; ++r)
          dst[(((size_t)(b * NH + h) * S_ + s0 + r) << 6) + d] = f2bf((acc[m][n][r] + bv) * scl);
      }
    }
  }
}

// Out-projection GEMM (round-16 verified): M-split 64x128, XCD-grouped decode.
__global__ __launch_bounds__(256)
void gemm_out_m64(const u16* __restrict__ A, const u16* __restrict__ W,
                  const float* __restrict__ bias, float* __restrict__ Cf,
                  int M, int N, int K) {
  __shared__ u16 Als[2][64 * 32];
  __shared__ u16 Bls[2][128 * 32];
  const int tid  = threadIdx.x;
  const int wave = tid >> 6, lane = tid & 63;
  const int lhi  = lane >> 4, llo = lane & 15;
  const int wr   = wave >> 1, wc = wave & 1;
  const int bid  = blockIdx.x;               // 0..511
  const int xcd  = bid & 7, i = bid >> 3;    // i: 0..63
  const int m0   = (xcd * 8 + (i & 7)) * 64;
  const int n0   = (i >> 3) * 128;
  const int KT   = K >> 5;

  f32x4 acc[2][4];
#pragma unroll
  for (int m = 0; m < 2; ++m)
#pragma unroll
    for (int n = 0; n < 4; ++n) acc[m][n] = f32x4{0.f, 0.f, 0.f, 0.f};

  auto issue = [&](int t) {
    {
      const int row = tid >> 2, col = (tid & 3) * 8;
      gload16(A + (size_t)(m0 + row) * K + t * 32 + col,
              (char*)Als[t & 1] + wave * 1024);
    }
#pragma unroll
    for (int j = 0; j < 2; ++j) {
      const int e   = (tid + j * 256) * 8;
      const int row = e >> 5, col = e & 31;
      gload16(W + (size_t)(n0 + row) * K + t * 32 + col,
              (char*)Bls[t & 1] + wave * 1024 + j * 4096);
    }
  };

  issue(0);                                        // 3 outstanding
  for (int t = 0; t < KT; ++t) {
    if (t + 1 < KT) {
      issue(t + 1);                                // 6 outstanding
      asm volatile("s_waitcnt vmcnt(3)" ::: "memory");  // tile t landed
    } else {
      asm volatile("s_waitcnt vmcnt(0)" ::: "memory");
    }
    BARRIER();
    const u16* Ab = Als[t & 1];
    const u16* Bb = Bls[t & 1];
    bf16x8 af[2], bfr[4];
#pragma unroll
    for (int m = 0; m < 2; ++m) af[m]  = *(const bf16x8*)&Ab[(wr * 32 + m * 16 + llo) * 32 + lhi * 8];
#pragma unroll
    for (int n = 0; n < 4; ++n) bfr[n] = *(const bf16x8*)&Bb[(wc * 64 + n * 16 + llo) * 32 + lhi * 8];
#pragma unroll
    for (int m = 0; m < 2; ++m)
#pragma unroll
      for (int n = 0; n < 4; ++n)
        acc[m][n] = __builtin_amdgcn_mfma_f32_16x16x32_bf16(af[m], bfr[n], acc[m][n], 0, 0, 0);
    BARRIER();
  }

#pragma unroll
  for (int n = 0; n < 4; ++n) {
    const int gcol = n0 + wc * 64 + n * 16 + llo;
    const float bv = bias[gcol];
#pragma unroll
    for (int m = 0; m < 2; ++m) {
      const int rowb = m0 + wr * 32 + m * 16 + lhi * 4;
#pragma unroll
      for (int r = 0; r < 4; ++r)
        Cf[(size_t)(rowb + r) * N + gcol] = acc[m][n][r] + bv;
    }
  }
}

// Flash attention fwd (round-16 base): 32x32x16 MFMA, permuted K-row reads,
// defer-max, quad-buffered K/V^T, counted vmcnt, even/odd software pipeline,
// XCD-grouped grid decode, VALU lsum adds. ROUND-19: both per-tile
// __shfl_xor(.,32) bpermutes removed from the common-case serial chain --
// (1) defer-max trigger uses per-lane local max (__any spans all 64 lanes, so
// the tested value-set is identical); true row max computed only inside the
// rare wave-uniform rescale branch; (2) lsum kept as per-lane partial (alpha
// is row-uniform so partial rescale is exact); single cross-half sum shfl at
// finalize.
__global__ __launch_bounds__(256, 2)
void attn_fwd(const u16* __restrict__ Qb, const u16* __restrict__ Kb,
              const u16* __restrict__ VbT, u16* __restrict__ Obf) {
  __shared__ __align__(16) u16 Kls[4][KVB * HD];
  __shared__ __align__(16) u16 Vls[4][HD * KVB];
  __shared__ __align__(16) float sBc[4][32];
  const int tid  = threadIdx.x;
  const int wave = tid >> 6, lane = tid & 63;
  const int q    = lane & 31, hi = lane >> 5;
  const int bid  = blockIdx.x;               // 0..511
  const int g    = bid >> 3;                 // 0..63
  const int bh   = (bid & 7) * 4 + (g >> 4); // 0..31
  const int q0   = (g & 15) * QBLK;
  const size_t base  = (size_t)bh * S_ * HD;
  const size_t basev = (size_t)bh * HD * S_;

  const int qrow = q0 + wave * 32 + q;
  bf16x8 qf[4];
#pragma unroll
  for (int c = 0; c < 4; ++c)
    qf[c] = *(const bf16x8*)&Qb[base + (size_t)qrow * HD + c * 16 + hi * 8];

  const int srow = tid >> 3;
  const int xs   = (tid & 7) ^ (srow & 7);
  const u16* kSrc = Kb  + base  + (size_t)srow * HD + xs * 8;
  const u16* vSrc = VbT + basev + (size_t)srow * S_ + xs * 8;
  const int ldsW = wave * 1024;

  const int gq = 16 * (q >> 4) + 8 * ((q >> 2) & 1) + (q & 3) + 4 * ((q >> 3) & 1);
  int offK[2][4], offV[2][4];
#pragma unroll
  for (int b = 0; b < 2; ++b)
#pragma unroll
    for (int c = 0; c < 4; ++c) {
      offK[b][c] = (b * 32 + gq) * 128 + (((c * 2 + hi) ^ (gq & 7)) << 4);
      offV[b][c] = (b * 32 + q)  * 128 + (((c * 2 + hi) ^ (q  & 7)) << 4);
    }

  f32x16 o0, o1, z16;
#pragma unroll
  for (int r = 0; r < 16; ++r) { o0[r] = 0.f; o1[r] = 0.f; z16[r] = 0.f; }
  float m_run = -1e30f, lsum = 0.f;            // lsum: per-lane PARTIAL

  auto issue = [&](int t) {
#pragma unroll
    for (int p = 0; p < 2; ++p) {
      gload16(kSrc + (size_t)t * KVB * HD + (size_t)p * 32 * HD,
              (char*)Kls[t & 3] + p * 4096 + ldsW);
      gload16(vSrc + t * KVB + (size_t)p * 32 * S_,
              (char*)Vls[t & 3] + p * 4096 + ldsW);
    }
  };

  auto qk = [&](int t, f32x16& s0, f32x16& s1) {
    const char* Kt = (const char*)Kls[t & 3];
    {
      bf16x8 k0 = *(const bf16x8*)(Kt + offK[0][0]);
      bf16x8 k1 = *(const bf16x8*)(Kt + offK[1][0]);
      s0 = __builtin_amdgcn_mfma_f32_32x32x16_bf16(k0, qf[0], z16, 0, 0, 0);
      s1 = __builtin_amdgcn_mfma_f32_32x32x16_bf16(k1, qf[0], z16, 0, 0, 0);
    }
#pragma unroll
    for (int c = 1; c < 4; ++c) {
      bf16x8 k0 = *(const bf16x8*)(Kt + offK[0][c]);
      bf16x8 k1 = *(const bf16x8*)(Kt + offK[1][c]);
      s0 = __builtin_amdgcn_mfma_f32_32x32x16_bf16(k0, qf[c], s0, 0, 0, 0);
      s1 = __builtin_amdgcn_mfma_f32_32x32x16_bf16(k1, qf[c], s1, 0, 0, 0);
    }
  };

  // online softmax: per-lane local max for the trigger (no shfl on the common
  // path); true row max + rescale only in the rare wave-uniform branch.
  auto sm = [&](f32x16& s0, f32x16& s1, u32 (&dw0)[8], u32 (&dw1)[8]) {
    float tm[16];
#pragma unroll
    for (int r = 0; r < 16; ++r) tm[r] = fmaxf(s0[r], s1[r]);
#pragma unroll
    for (int st = 8; st >= 1; st >>= 1)
#pragma unroll
      for (int i = 0; i < 16; ++i) if (i < st) tm[i] = fmaxf(tm[i], tm[i + st]);
    // tm[0] = this lane's local max over its 32 kv values

    if (__any(tm[0] > m_run + 10.0f)) {
      const float pm   = fmaxf(tm[0], __shfl_xor(tm[0], 32));  // true row max
      const float mnew = fmaxf(m_run, pm);
      const float alpha = exp2f(m_run - mnew);
      sBc[wave][q] = alpha;
      asm volatile("s_waitcnt lgkmcnt(0)" ::: "memory");
      f32x4 av[4];
#pragma unroll
      for (int gg = 0; gg < 4; ++gg) av[gg] = *(const f32x4*)&sBc[wave][hi * 4 + gg * 8];
#pragma unroll
      for (int r = 0; r < 16; ++r) {
        const float f = av[r >> 2][r & 3];
        o0[r] *= f; o1[r] *= f;
      }
      lsum *= alpha;                      // partial rescale: alpha row-uniform
      m_run = mnew;
    }

    float t0 = 0.f, t1 = 0.f, t2 = 0.f, t3 = 0.f;
#pragma unroll
    for (int j = 0; j < 8; ++j) {
      const float a0 = exp2f(s0[2 * j] - m_run), a1 = exp2f(s0[2 * j + 1] - m_run);
      const float b0 = exp2f(s1[2 * j] - m_run), b1 = exp2f(s1[2 * j + 1] - m_run);
      t0 += a0; t1 += a1; t2 += b0; t3 += b1;
      dw0[j] = cvtpk(a0, a1);
      dw1[j] = cvtpk(b0, b1);
    }
    lsum += (t0 + t1) + (t2 + t3);        // per-lane partial; no shfl here
  };

  auto pv = [&](int t, u32 (&dw0)[8], u32 (&dw1)[8]) {
    const char* Vt = (const char*)Vls[t & 3];
#pragma unroll
    for (int c = 0; c < 4; ++c) {
      union { u32 u[4]; bf16x8 v; } P;
      if (c == 0)      { P.u[0] = dw0[0]; P.u[1] = dw0[1]; P.u[2] = dw0[2]; P.u[3] = dw0[3]; }
      else if (c == 1) { P.u[0] = dw0[4]; P.u[1] = dw0[5]; P.u[2] = dw0[6]; P.u[3] = dw0[7]; }
      else if (c == 2) { P.u[0] = dw1[0]; P.u[1] = dw1[1]; P.u[2] = dw1[2]; P.u[3] = dw1[3]; }
      else             { P.u[0] = dw1[4]; P.u[1] = dw1[5]; P.u[2] = dw1[6]; P.u[3] = dw1[7]; }
      bf16x8 v0 = *(const bf16x8*)(Vt + offV[0][c]);
      bf16x8 v1 = *(const bf16x8*)(Vt + offV[1][c]);
      o0 = __builtin_amdgcn_mfma_f32_32x32x16_bf16(P.v, v0, o0, 0, 0, 0);
      o1 = __builtin_amdgcn_mfma_f32_32x32x16_bf16(P.v, v1, o1, 0, 0, 0);
    }
  };

  f32x16 sE0, sE1, sO0, sO1;
  u32 dwE0[8], dwE1[8], dwO0[8], dwO1[8];

  issue(0); issue(1);
  for (int p = 0; p < NT / 2 - 1; ++p) {
    issue(2 * p + 2); issue(2 * p + 3);
    asm volatile("s_waitcnt vmcnt(8)" ::: "memory");  // pair p landed
    BARRIER();
    qk(2 * p,     sE0, sE1);          // MFMA
    qk(2 * p + 1, sO0, sO1);          // MFMA, independent -> overlaps sm(e)
    sm(sE0, sE1, dwE0, dwE1);         // VALU
    pv(2 * p,     dwE0, dwE1);        // MFMA -> overlaps sm(o) exp/pack
    sm(sO0, sO1, dwO0, dwO1);         // VALU
    pv(2 * p + 1, dwO0, dwO1);        // MFMA
    BARRIER();                        // pair p bufs free for reuse
  }
  asm volatile("s_waitcnt vmcnt(0)" ::: "memory");
  BARRIER();
  qk(NT - 2, sE0, sE1);
  qk(NT - 1, sO0, sO1);
  sm(sE0, sE1, dwE0, dwE1);
  pv(NT - 2, dwE0, dwE1);
  sm(sO0, sO1, dwO0, dwO1);
  pv(NT - 1, dwO0, dwO1);

  // ---- finalize: complete the deferred cross-half sum, then broadcast ----
  lsum += __shfl_xor(lsum, 32);                // full row sum
  const float li = 1.0f / lsum;
  sBc[wave][q] = li;                           // lanes q, q+32: same value
  asm volatile("s_waitcnt lgkmcnt(0)" ::: "memory");
  f32x4 lv[4];
#pragma unroll
  for (int gg = 0; gg < 4; ++gg) lv[gg] = *(const f32x4*)&sBc[wave][hi * 4 + gg * 8];
  const int b = bh >> 4, h = bh & 15;
#pragma unroll
  for (int r = 0; r < 16; ++r) {
    const int qg = q0 + wave * 32 + (r & 3) + 8 * (r >> 2) + 4 * hi;
    const float f = lv[r >> 2][r & 3];
    u16* dst = Obf + ((size_t)(b * S_ + qg) * NH + h) * HD;
    dst[q]      = f2bf(o0[r] * f);
    dst[32 + q] = f2bf(o1[r] * f);
  }
}

extern "C" void kernel_launch(void* const* d_in, const int* in_sizes, int n_in,
                              void* d_out, int out_size, void* d_ws, size_t ws_size,
                              hipStream_t stream) {
  const float* x     = (const float*)d_in[0];
  const float* qkv_w = (const float*)d_in[1];
  const float* qkv_b = (const float*)d_in[2];
  const float* o_w   = (const float*)d_in[3];
  const float* o_b   = (const float*)d_in[4];
  float* out = (float*)d_out;

  char* ws = (char*)d_ws;
  u16* xbf  = (u16*)(ws);                     // 8 MB; later aliased as attn output
  u16* wqkv = (u16*)(ws + (8u  << 20));       // 6 MB
  u16* wo   = (u16*)(ws + (14u << 20));       // 2 MB
  u16* Qb   = (u16*)(ws + (16u << 20));       // 8 MB  [B,H,S,d]
  u16* Kb   = (u16*)(ws + (24u << 20));       // 8 MB  [B,H,S,d]
  u16* VbT  = (u16*)(ws + (32u << 20));       // 8 MB  [B,H,d,S]
  u16* atnb = xbf;                            // [B,S,H,d] bf16 (x_bf dead by then)

  cast_all<<<8192, 256, 0, stream>>>(x, qkv_w, o_w, xbf, wqkv, wo);

  gemm_qkv<<<768, 256, 0, stream>>>(xbf, wqkv, qkv_b, Qb, Kb, VbT);

  attn_fwd<<<512, 256, 0, stream>>>(Qb, Kb, VbT, atnb);

  gemm_out_m64<<<512, 256, 0, stream>>>(atnb, wo, o_b, out, MROWS, EMB, EMB);
}